// Round 3
// baseline (763.110 us; speedup 1.0000x reference)
//
#include <hip/hip_runtime.h>

#define NNODES 100000
#define NEDGES 1000000
#define DIM 64
#define NGRAPHS 128
#define NLAYERS 3
#define BN_EPS 1e-5f

#define NBINS 3125          // 32 nodes per bin, 3125*32 == NNODES exactly
#define GBLK 64             // blocks for count/scatter passes

// workspace layout (4-byte element offsets)
#define OFF_EDGES   0            // int2[NEDGES] = 2,000,000 ints
#define OFF_BINBASE 2000000      // int[NBINS+1]
#define OFF_AGG     2003200      // float[NNODES*64]
#define OFF_Y       8403200      // float[NNODES*64]
// counts/offsets/binTotal live inside the (not yet used) Y region during preprocessing
#define OFF_COUNTS  8403200      // int[NBINS*GBLK] = 200,000
#define OFF_OFFS    8603200      // int[NBINS*GBLK] = 200,000
#define OFF_BTOT    8803200      // int[NBINS]
// stats region
#define OFF_SCALE   14803200     // float[NLAYERS*64]
#define OFF_SHIFT   14803392     // float[NLAYERS*64]
#define OFF_GSUM    14803584     // float[NGRAPHS*64]
#define OFF_PS      14811776     // float[NGRAPHS*64]
#define OFF_PQ      14819968     // float[NGRAPHS*64]
#define OFF_END     14828160     // int[NGRAPHS]

// ---- preprocessing: bin 1M edges by dst>>5 with zero global atomics ----

__global__ __launch_bounds__(1024) void count_kernel(const int* __restrict__ ei,
                                                     int* __restrict__ counts) {
    __shared__ int hist[NBINS];
    const int tid = threadIdx.x, blk = blockIdx.x;
    for (int i = tid; i < NBINS; i += 1024) hist[i] = 0;
    __syncthreads();
    const int e0 = blk * (NEDGES / GBLK), e1 = e0 + (NEDGES / GBLK);
    for (int e = e0 + tid; e < e1; e += 1024)
        atomicAdd(&hist[ei[NEDGES + e] >> 5], 1);
    __syncthreads();
    for (int bin = tid; bin < NBINS; bin += 1024)
        counts[bin * GBLK + blk] = hist[bin];
}

// one wave per bin: exclusive scan of the 64 per-block counts + bin total
__global__ __launch_bounds__(256) void s1_kernel(const int* __restrict__ counts,
                                                 int* __restrict__ offs,
                                                 int* __restrict__ btot) {
    const int bin = blockIdx.x * 4 + (threadIdx.x >> 6);
    const int lane = threadIdx.x & 63;
    if (bin >= NBINS) return;
    const int v = counts[bin * GBLK + lane];
    int s = v;
    for (int off = 1; off < 64; off <<= 1) {
        int t = __shfl_up(s, off);
        if (lane >= off) s += t;
    }
    offs[bin * GBLK + lane] = s - v;
    if (lane == 63) btot[bin] = s;
}

// single-block exclusive scan over NBINS bin totals -> binBase (+ sentinel)
__global__ __launch_bounds__(1024) void s2_kernel(const int* __restrict__ btot,
                                                  int* __restrict__ binBase) {
    __shared__ int s[1024];
    const int t = threadIdx.x;
    int running = 0;
    for (int base = 0; base < NBINS; base += 1024) {
        const int i = base + t;
        const int v = (i < NBINS) ? btot[i] : 0;
        __syncthreads();
        s[t] = v;
        __syncthreads();
        for (int off = 1; off < 1024; off <<= 1) {
            int x = (t >= off) ? s[t - off] : 0;
            __syncthreads();
            s[t] += x;
            __syncthreads();
        }
        if (i < NBINS) binBase[i] = running + s[t] - v;
        running += s[1023];
    }
    if (t == 0) binBase[NBINS] = running;
}

__global__ __launch_bounds__(1024) void scatter_kernel(const int* __restrict__ ei,
                                                       const float* __restrict__ ea,
                                                       const int* __restrict__ binBase,
                                                       const int* __restrict__ offs,
                                                       int2* __restrict__ edges) {
    __shared__ int cur[NBINS];
    const int tid = threadIdx.x, blk = blockIdx.x;
    for (int i = tid; i < NBINS; i += 1024)
        cur[i] = binBase[i] + offs[i * GBLK + blk];
    __syncthreads();
    const int e0 = blk * (NEDGES / GBLK), e1 = e0 + (NEDGES / GBLK);
    for (int e = e0 + tid; e < e1; e += 1024) {
        const int dst = ei[NEDGES + e];
        const int src = ei[e];
        const float w = ea[e];
        const int pos = atomicAdd(&cur[dst >> 5], 1);   // LDS atomic
        edges[pos] = make_int2((src << 5) | (dst & 31), __float_as_int(w));
    }
}

// per-graph end offsets from the sorted batch vector (no atomics)
__global__ __launch_bounds__(1024) void bounds_kernel(const int* __restrict__ batch,
                                                      int* __restrict__ endv) {
    const int i = blockIdx.x * 1024 + threadIdx.x;
    if (i >= NNODES) return;
    const int b0 = batch[i];
    const int b1 = (i + 1 < NNODES) ? batch[i + 1] : NGRAPHS;
    for (int g = b0; g < b1; ++g) endv[g] = i + 1;
    if (i == 0)
        for (int g = 0; g < b0; ++g) endv[g] = 0;
}

// ---- aggregation: wave per bin, private 8 KB LDS accumulator (no atomics) ----
template <bool FIRST>
__global__ __launch_bounds__(256) void agg_kernel(const float* __restrict__ h,
                                                  const float* __restrict__ scale,
                                                  const float* __restrict__ shift,
                                                  const int* __restrict__ binBase,
                                                  const int2* __restrict__ edges,
                                                  float* __restrict__ agg) {
    __shared__ float accAll[4][32 * 64];
    const int w = threadIdx.x >> 6, lane = threadIdx.x & 63;
    const int bin = blockIdx.x * 4 + w;
    if (bin >= NBINS) return;             // whole-wave exit; no __syncthreads below
    float* acc = accAll[w];
#pragma unroll
    for (int r = 0; r < 32; ++r) acc[r * 64 + lane] = 0.f;
    const float sc = FIRST ? 1.f : scale[lane];
    const float sh = FIRST ? 0.f : shift[lane];
    const int beg = binBase[bin], end = binBase[bin + 1];
    for (int j = beg; j < end; j += 64) {
        const int n = min(64, end - j);
        int2 ed = (j + lane < end) ? edges[j + lane] : make_int2(0, 0);
        for (int t = 0; t < n; ++t) {
            const int sd = __shfl(ed.x, t);
            const float wt = __int_as_float(__shfl(ed.y, t));
            const float hv = h[(sd >> 5) * 64 + lane];
            const float m = FIRST ? hv * wt : fmaf(hv, sc, sh) * wt;
            acc[(sd & 31) * 64 + lane] += m;
        }
    }
    const int nodeBase = bin * 32;
#pragma unroll
    for (int r = 0; r < 32; ++r)
        agg[(nodeBase + r) * 64 + lane] = acc[r * 64 + lane];
}

// ---- y = PReLU(agg @ W^T + bias), thread-per-row, W via wave-uniform loads ----
__global__ __launch_bounds__(256) void gemm_kernel(const float* __restrict__ agg,
                                                   const float* __restrict__ W,
                                                   const float* __restrict__ bias,
                                                   const float* __restrict__ pa_ptr,
                                                   float* __restrict__ y) {
    __shared__ float tile[4][64 * 17];
    const int wv = threadIdx.x >> 6, lane = threadIdx.x & 63;
    const int base = (blockIdx.x * 4 + wv) * 64;
    if (base >= NNODES) return;           // whole-wave exit
    const int row = base + lane;
    const float pa = *pa_ptr;
    float a[64];
    if (row < NNODES) {
        const float4* ap = (const float4*)(agg + row * 64);
#pragma unroll
        for (int i = 0; i < 16; ++i) {
            float4 t = ap[i];
            a[4 * i] = t.x; a[4 * i + 1] = t.y; a[4 * i + 2] = t.z; a[4 * i + 3] = t.w;
        }
    } else {
#pragma unroll
        for (int i = 0; i < 64; ++i) a[i] = 0.f;
    }
    float* tl = tile[wv];
    for (int cc = 0; cc < 4; ++cc) {
#pragma unroll
        for (int ci = 0; ci < 16; ++ci) {
            const int c = cc * 16 + ci;
            const float* wr = W + c * 64;
            float acc = bias[c];
#pragma unroll
            for (int k = 0; k < 64; k += 4) {
                const float4 w4 = *(const float4*)(wr + k);
                acc += a[k] * w4.x + a[k + 1] * w4.y + a[k + 2] * w4.z + a[k + 3] * w4.w;
            }
            const float v = (acc >= 0.f) ? acc : pa * acc;
            tl[lane * 17 + ci] = v;
        }
#pragma unroll
        for (int s = 0; s < 16; ++s) {
            const int idx = s * 64 + lane;
            const int rr = idx >> 4, cl = idx & 15;
            const int grow = base + rr;
            if (grow < NNODES) y[grow * 64 + cc * 16 + cl] = tl[rr * 17 + cl];
        }
    }
}

// ---- block-per-graph: per-graph sum + per-channel BN partials (no atomics) ----
__global__ __launch_bounds__(256) void stats_kernel(const float* __restrict__ y,
                                                    const int* __restrict__ endv,
                                                    float* __restrict__ gsum,
                                                    float* __restrict__ pS,
                                                    float* __restrict__ pQ) {
    __shared__ float red[3][4][64];
    const int g = blockIdx.x;
    const int w = threadIdx.x >> 6, lane = threadIdx.x & 63;
    const int r0 = (g == 0) ? 0 : endv[g - 1];
    const int r1 = endv[g];
    float ga = 0.f, ls = 0.f, lsq = 0.f;
    for (int r = r0 + w; r < r1; r += 4) {
        const float v = y[r * 64 + lane];
        ga += v; ls += v; lsq = fmaf(v, v, lsq);
    }
    red[0][w][lane] = ga; red[1][w][lane] = ls; red[2][w][lane] = lsq;
    __syncthreads();
    if (w == 0) {
        float a = 0.f, b = 0.f, c = 0.f;
#pragma unroll
        for (int k = 0; k < 4; ++k) {
            a += red[0][k][lane]; b += red[1][k][lane]; c += red[2][k][lane];
        }
        gsum[g * 64 + lane] = a;
        pS[g * 64 + lane] = b;
        pQ[g * 64 + lane] = c;
    }
}

// ---- single block: BN closure + pooled outputs straight into d_out ----
__global__ __launch_bounds__(1024) void finalize_kernel(const float* __restrict__ gsum,
                                                        const float* __restrict__ pS,
                                                        const float* __restrict__ pQ,
                                                        const int* __restrict__ endv,
                                                        const float* __restrict__ bn_w,
                                                        const float* __restrict__ bn_b,
                                                        float* __restrict__ scale,
                                                        float* __restrict__ shift,
                                                        float* __restrict__ out, int layer) {
    __shared__ float ssc[64], ssh[64];
    const int tid = threadIdx.x;
    if (tid < 64) {
        float s = 0.f, q = 0.f;
        for (int g = 0; g < NGRAPHS; ++g) {
            s += pS[g * 64 + tid];
            q += pQ[g * 64 + tid];
        }
        const float mean = s * (1.f / NNODES);
        const float var = fmaxf(q * (1.f / NNODES) - mean * mean, 0.f);
        const float inv = rsqrtf(var + BN_EPS);
        const float sc = inv * bn_w[tid];
        const float sh = bn_b[tid] - mean * sc;
        ssc[tid] = sc; ssh[tid] = sh;
        scale[tid] = sc; shift[tid] = sh;
    }
    __syncthreads();
    for (int idx = tid; idx < NGRAPHS * 64; idx += 1024) {
        const int g = idx >> 6, c = idx & 63;
        const int cnt = endv[g] - ((g == 0) ? 0 : endv[g - 1]);
        const float pooled = gsum[idx] * ssc[c] + (float)cnt * ssh[c];
        out[g * (NLAYERS * 64) + layer * 64 + c] = pooled;
        if (layer == NLAYERS - 1) out[NGRAPHS * NLAYERS * 64 + idx] = pooled;
    }
}

extern "C" void kernel_launch(void* const* d_in, const int* in_sizes, int n_in,
                              void* d_out, int out_size, void* d_ws, size_t ws_size,
                              hipStream_t stream) {
    const float* x     = (const float*)d_in[0];
    const int*   ei    = (const int*)d_in[1];
    const float* ea    = (const float*)d_in[2];
    const int*   batch = (const int*)d_in[3];
    const float* W     = (const float*)d_in[4];
    const float* b     = (const float*)d_in[5];
    const float* pa    = (const float*)d_in[6];
    const float* bn_w  = (const float*)d_in[7];
    const float* bn_b  = (const float*)d_in[8];
    float* out = (float*)d_out;
    float* ws  = (float*)d_ws;
    int*   wsi = (int*)d_ws;

    int2*  edges   = (int2*)(wsi + OFF_EDGES);
    int*   binBase = wsi + OFF_BINBASE;
    float* agg     = ws + OFF_AGG;
    float* y       = ws + OFF_Y;
    int*   counts  = wsi + OFF_COUNTS;
    int*   offs    = wsi + OFF_OFFS;
    int*   btot    = wsi + OFF_BTOT;
    float* scaleA  = ws + OFF_SCALE;
    float* shiftA  = ws + OFF_SHIFT;
    float* gsum    = ws + OFF_GSUM;
    float* pS      = ws + OFF_PS;
    float* pQ      = ws + OFF_PQ;
    int*   endv    = wsi + OFF_END;

    count_kernel<<<GBLK, 1024, 0, stream>>>(ei, counts);
    s1_kernel<<<(NBINS + 3) / 4, 256, 0, stream>>>(counts, offs, btot);
    s2_kernel<<<1, 1024, 0, stream>>>(btot, binBase);
    scatter_kernel<<<GBLK, 1024, 0, stream>>>(ei, ea, binBase, offs, edges);
    bounds_kernel<<<(NNODES + 1023) / 1024, 1024, 0, stream>>>(batch, endv);

    for (int l = 0; l < NLAYERS; ++l) {
        if (l == 0)
            agg_kernel<true><<<(NBINS + 3) / 4, 256, 0, stream>>>(x, nullptr, nullptr,
                                                                  binBase, edges, agg);
        else
            agg_kernel<false><<<(NBINS + 3) / 4, 256, 0, stream>>>(y, scaleA + (l - 1) * 64,
                                                                   shiftA + (l - 1) * 64,
                                                                   binBase, edges, agg);
        gemm_kernel<<<391, 256, 0, stream>>>(agg, W + l * 4096, b + l * 64, pa, y);
        stats_kernel<<<NGRAPHS, 256, 0, stream>>>(y, endv, gsum, pS, pQ);
        finalize_kernel<<<1, 1024, 0, stream>>>(gsum, pS, pQ, endv, bn_w + l * 64,
                                                bn_b + l * 64, scaleA + l * 64,
                                                shiftA + l * 64, out, l);
    }
}

// Round 4
// 467.761 us; speedup vs baseline: 1.6314x; 1.6314x over previous
//
#include <hip/hip_runtime.h>

#define NNODES 100000
#define NEDGES 1000000
#define DIM 64
#define NGRAPHS 128
#define NLAYERS 3
#define BN_EPS 1e-5f

#define BINSZ 16
#define NBINS 6250          // 16 nodes per bin, 6250*16 == NNODES exactly
#define GBLK 64             // blocks for count/scatter passes

// workspace layout (4-byte element offsets)
#define OFF_EDGES   0            // int2[NEDGES] = 2,000,000 ints
#define OFF_BINBASE 2000000      // int[NBINS+1]
#define OFF_AGG     2006272      // float[NNODES*64]
#define OFF_Y       8406272      // float[NNODES*64]
// counts/offsets/binTotal overlay the (not yet used) Y region during preprocessing
#define OFF_COUNTS  8406272      // int[NBINS*GBLK] = 400,000
#define OFF_OFFS    8806272      // int[NBINS*GBLK] = 400,000
#define OFF_BTOT    9206272      // int[NBINS]
// stats region
#define OFF_SCALE   14806272     // float[NLAYERS*64]
#define OFF_SHIFT   14806464     // float[NLAYERS*64]
#define OFF_GSUM    14806656     // float[NGRAPHS*64]
#define OFF_PS      14814848     // float[NGRAPHS*64]
#define OFF_PQ      14823040     // float[NGRAPHS*64]
#define OFF_END     14831232     // int[NGRAPHS]

// ---- preprocessing: bin 1M edges by dst>>4 with zero global atomics ----

__global__ __launch_bounds__(1024) void count_kernel(const int* __restrict__ ei,
                                                     int* __restrict__ counts) {
    __shared__ int hist[NBINS];
    const int tid = threadIdx.x, blk = blockIdx.x;
    for (int i = tid; i < NBINS; i += 1024) hist[i] = 0;
    __syncthreads();
    const int e0 = blk * (NEDGES / GBLK), e1 = e0 + (NEDGES / GBLK);
    for (int e = e0 + tid; e < e1; e += 1024)
        atomicAdd(&hist[ei[NEDGES + e] / BINSZ], 1);
    __syncthreads();
    for (int bin = tid; bin < NBINS; bin += 1024)
        counts[bin * GBLK + blk] = hist[bin];
}

// one wave per bin: exclusive scan of the 64 per-block counts + bin total
__global__ __launch_bounds__(256) void s1_kernel(const int* __restrict__ counts,
                                                 int* __restrict__ offs,
                                                 int* __restrict__ btot) {
    const int bin = blockIdx.x * 4 + (threadIdx.x >> 6);
    const int lane = threadIdx.x & 63;
    if (bin >= NBINS) return;
    const int v = counts[bin * GBLK + lane];
    int s = v;
    for (int off = 1; off < 64; off <<= 1) {
        int t = __shfl_up(s, off);
        if (lane >= off) s += t;
    }
    offs[bin * GBLK + lane] = s - v;
    if (lane == 63) btot[bin] = s;
}

// single-block exclusive scan over NBINS bin totals -> binBase (+ sentinel)
__global__ __launch_bounds__(1024) void s2_kernel(const int* __restrict__ btot,
                                                  int* __restrict__ binBase) {
    __shared__ int s[1024];
    const int t = threadIdx.x;
    int running = 0;
    for (int base = 0; base < NBINS; base += 1024) {
        const int i = base + t;
        const int v = (i < NBINS) ? btot[i] : 0;
        __syncthreads();
        s[t] = v;
        __syncthreads();
        for (int off = 1; off < 1024; off <<= 1) {
            int x = (t >= off) ? s[t - off] : 0;
            __syncthreads();
            s[t] += x;
            __syncthreads();
        }
        if (i < NBINS) binBase[i] = running + s[t] - v;
        running += s[1023];
    }
    if (t == 0) binBase[NBINS] = running;
}

__global__ __launch_bounds__(1024) void scatter_kernel(const int* __restrict__ ei,
                                                       const float* __restrict__ ea,
                                                       const int* __restrict__ binBase,
                                                       const int* __restrict__ offs,
                                                       int2* __restrict__ edges) {
    __shared__ int cur[NBINS];
    const int tid = threadIdx.x, blk = blockIdx.x;
    for (int i = tid; i < NBINS; i += 1024)
        cur[i] = binBase[i] + offs[i * GBLK + blk];
    __syncthreads();
    const int e0 = blk * (NEDGES / GBLK), e1 = e0 + (NEDGES / GBLK);
    for (int e = e0 + tid; e < e1; e += 1024) {
        const int dst = ei[NEDGES + e];
        const int src = ei[e];
        const float w = ea[e];
        const int pos = atomicAdd(&cur[dst / BINSZ], 1);   // LDS atomic
        edges[pos] = make_int2((src << 4) | (dst & (BINSZ - 1)), __float_as_int(w));
    }
}

// per-graph end offsets from the sorted batch vector (no atomics)
__global__ __launch_bounds__(1024) void bounds_kernel(const int* __restrict__ batch,
                                                      int* __restrict__ endv) {
    const int i = blockIdx.x * 1024 + threadIdx.x;
    if (i >= NNODES) return;
    const int b0 = batch[i];
    const int b1 = (i + 1 < NNODES) ? batch[i + 1] : NGRAPHS;
    for (int g = b0; g < b1; ++g) endv[g] = i + 1;
    if (i == 0)
        for (int g = 0; g < b0; ++g) endv[g] = 0;
}

// ---- aggregation: wave per 16-node bin, private 4 KB LDS accumulator,
// 4-deep unrolled gather for ILP (no atomics) ----
template <bool FIRST>
__global__ __launch_bounds__(256) void agg_kernel(const float* __restrict__ h,
                                                  const float* __restrict__ scale,
                                                  const float* __restrict__ shift,
                                                  const int* __restrict__ binBase,
                                                  const int2* __restrict__ edges,
                                                  float* __restrict__ agg) {
    __shared__ float accAll[4][BINSZ * 64];   // 16 KB / block
    const int w = threadIdx.x >> 6, lane = threadIdx.x & 63;
    const int bin = blockIdx.x * 4 + w;
    if (bin >= NBINS) return;             // whole-wave exit; no __syncthreads below
    float* acc = accAll[w];
#pragma unroll
    for (int r = 0; r < BINSZ; ++r) acc[r * 64 + lane] = 0.f;
    const float sc = FIRST ? 1.f : scale[lane];
    const float sh = FIRST ? 0.f : shift[lane];
    const int beg = binBase[bin], end = binBase[bin + 1];
    for (int j = beg; j < end; j += 64) {
        const int n = min(64, end - j);
        int2 ed = (j + lane < end) ? edges[j + lane] : make_int2(0, 0);
        const int n4 = n & ~3;
        int t = 0;
        for (; t < n4; t += 4) {
            const int s0 = __shfl(ed.x, t);
            const int s1 = __shfl(ed.x, t + 1);
            const int s2 = __shfl(ed.x, t + 2);
            const int s3 = __shfl(ed.x, t + 3);
            const float w0 = __int_as_float(__shfl(ed.y, t));
            const float w1 = __int_as_float(__shfl(ed.y, t + 1));
            const float w2 = __int_as_float(__shfl(ed.y, t + 2));
            const float w3 = __int_as_float(__shfl(ed.y, t + 3));
            float h0 = h[(s0 >> 4) * 64 + lane];
            float h1 = h[(s1 >> 4) * 64 + lane];
            float h2 = h[(s2 >> 4) * 64 + lane];
            float h3 = h[(s3 >> 4) * 64 + lane];
            if (!FIRST) {
                h0 = fmaf(h0, sc, sh); h1 = fmaf(h1, sc, sh);
                h2 = fmaf(h2, sc, sh); h3 = fmaf(h3, sc, sh);
            }
            acc[(s0 & 15) * 64 + lane] += w0 * h0;
            acc[(s1 & 15) * 64 + lane] += w1 * h1;
            acc[(s2 & 15) * 64 + lane] += w2 * h2;
            acc[(s3 & 15) * 64 + lane] += w3 * h3;
        }
        for (; t < n; ++t) {
            const int sd = __shfl(ed.x, t);
            const float wt = __int_as_float(__shfl(ed.y, t));
            float hv = h[(sd >> 4) * 64 + lane];
            if (!FIRST) hv = fmaf(hv, sc, sh);
            acc[(sd & 15) * 64 + lane] += wt * hv;
        }
    }
    const int nodeBase = bin * BINSZ;
#pragma unroll
    for (int r = 0; r < BINSZ; ++r)
        agg[(nodeBase + r) * 64 + lane] = acc[r * 64 + lane];
}

// ---- y = PReLU(agg @ W^T + bias), thread-per-row, W via wave-uniform loads ----
__global__ __launch_bounds__(256) void gemm_kernel(const float* __restrict__ agg,
                                                   const float* __restrict__ W,
                                                   const float* __restrict__ bias,
                                                   const float* __restrict__ pa_ptr,
                                                   float* __restrict__ y) {
    __shared__ float tile[4][64 * 17];
    const int wv = threadIdx.x >> 6, lane = threadIdx.x & 63;
    const int base = (blockIdx.x * 4 + wv) * 64;
    if (base >= NNODES) return;           // whole-wave exit
    const int row = base + lane;
    const float pa = *pa_ptr;
    float a[64];
    if (row < NNODES) {
        const float4* ap = (const float4*)(agg + row * 64);
#pragma unroll
        for (int i = 0; i < 16; ++i) {
            float4 t = ap[i];
            a[4 * i] = t.x; a[4 * i + 1] = t.y; a[4 * i + 2] = t.z; a[4 * i + 3] = t.w;
        }
    } else {
#pragma unroll
        for (int i = 0; i < 64; ++i) a[i] = 0.f;
    }
    float* tl = tile[wv];
    for (int cc = 0; cc < 4; ++cc) {
#pragma unroll
        for (int ci = 0; ci < 16; ++ci) {
            const int c = cc * 16 + ci;
            const float* wr = W + c * 64;
            float acc = bias[c];
#pragma unroll
            for (int k = 0; k < 64; k += 4) {
                const float4 w4 = *(const float4*)(wr + k);
                acc += a[k] * w4.x + a[k + 1] * w4.y + a[k + 2] * w4.z + a[k + 3] * w4.w;
            }
            const float v = (acc >= 0.f) ? acc : pa * acc;
            tl[lane * 17 + ci] = v;
        }
#pragma unroll
        for (int s = 0; s < 16; ++s) {
            const int idx = s * 64 + lane;
            const int rr = idx >> 4, cl = idx & 15;
            const int grow = base + rr;
            if (grow < NNODES) y[grow * 64 + cc * 16 + cl] = tl[rr * 17 + cl];
        }
    }
}

// ---- block-per-graph: per-graph sum + per-channel BN partials (no atomics) ----
__global__ __launch_bounds__(512) void stats_kernel(const float* __restrict__ y,
                                                    const int* __restrict__ endv,
                                                    float* __restrict__ gsum,
                                                    float* __restrict__ pS,
                                                    float* __restrict__ pQ) {
    __shared__ float red[3][8][64];
    const int g = blockIdx.x;
    const int w = threadIdx.x >> 6, lane = threadIdx.x & 63;
    const int r0 = (g == 0) ? 0 : endv[g - 1];
    const int r1 = endv[g];
    float ga = 0.f, ls = 0.f, lsq = 0.f;
    for (int r = r0 + w; r < r1; r += 8) {
        const float v = y[r * 64 + lane];
        ga += v; ls += v; lsq = fmaf(v, v, lsq);
    }
    red[0][w][lane] = ga; red[1][w][lane] = ls; red[2][w][lane] = lsq;
    __syncthreads();
    if (w == 0) {
        float a = 0.f, b = 0.f, c = 0.f;
#pragma unroll
        for (int k = 0; k < 8; ++k) {
            a += red[0][k][lane]; b += red[1][k][lane]; c += red[2][k][lane];
        }
        gsum[g * 64 + lane] = a;
        pS[g * 64 + lane] = b;
        pQ[g * 64 + lane] = c;
    }
}

// ---- single block: BN closure + pooled outputs straight into d_out ----
__global__ __launch_bounds__(1024) void finalize_kernel(const float* __restrict__ gsum,
                                                        const float* __restrict__ pS,
                                                        const float* __restrict__ pQ,
                                                        const int* __restrict__ endv,
                                                        const float* __restrict__ bn_w,
                                                        const float* __restrict__ bn_b,
                                                        float* __restrict__ scale,
                                                        float* __restrict__ shift,
                                                        float* __restrict__ out, int layer) {
    __shared__ float ssc[64], ssh[64];
    const int tid = threadIdx.x;
    if (tid < 64) {
        float s = 0.f, q = 0.f;
        for (int g = 0; g < NGRAPHS; ++g) {
            s += pS[g * 64 + tid];
            q += pQ[g * 64 + tid];
        }
        const float mean = s * (1.f / NNODES);
        const float var = fmaxf(q * (1.f / NNODES) - mean * mean, 0.f);
        const float inv = rsqrtf(var + BN_EPS);
        const float sc = inv * bn_w[tid];
        const float sh = bn_b[tid] - mean * sc;
        ssc[tid] = sc; ssh[tid] = sh;
        scale[tid] = sc; shift[tid] = sh;
    }
    __syncthreads();
    for (int idx = tid; idx < NGRAPHS * 64; idx += 1024) {
        const int g = idx >> 6, c = idx & 63;
        const int cnt = endv[g] - ((g == 0) ? 0 : endv[g - 1]);
        const float pooled = gsum[idx] * ssc[c] + (float)cnt * ssh[c];
        out[g * (NLAYERS * 64) + layer * 64 + c] = pooled;
        if (layer == NLAYERS - 1) out[NGRAPHS * NLAYERS * 64 + idx] = pooled;
    }
}

extern "C" void kernel_launch(void* const* d_in, const int* in_sizes, int n_in,
                              void* d_out, int out_size, void* d_ws, size_t ws_size,
                              hipStream_t stream) {
    const float* x     = (const float*)d_in[0];
    const int*   ei    = (const int*)d_in[1];
    const float* ea    = (const float*)d_in[2];
    const int*   batch = (const int*)d_in[3];
    const float* W     = (const float*)d_in[4];
    const float* b     = (const float*)d_in[5];
    const float* pa    = (const float*)d_in[6];
    const float* bn_w  = (const float*)d_in[7];
    const float* bn_b  = (const float*)d_in[8];
    float* out = (float*)d_out;
    float* ws  = (float*)d_ws;
    int*   wsi = (int*)d_ws;

    int2*  edges   = (int2*)(wsi + OFF_EDGES);
    int*   binBase = wsi + OFF_BINBASE;
    float* agg     = ws + OFF_AGG;
    float* y       = ws + OFF_Y;
    int*   counts  = wsi + OFF_COUNTS;
    int*   offs    = wsi + OFF_OFFS;
    int*   btot    = wsi + OFF_BTOT;
    float* scaleA  = ws + OFF_SCALE;
    float* shiftA  = ws + OFF_SHIFT;
    float* gsum    = ws + OFF_GSUM;
    float* pS      = ws + OFF_PS;
    float* pQ      = ws + OFF_PQ;
    int*   endv    = wsi + OFF_END;

    count_kernel<<<GBLK, 1024, 0, stream>>>(ei, counts);
    s1_kernel<<<(NBINS + 3) / 4, 256, 0, stream>>>(counts, offs, btot);
    s2_kernel<<<1, 1024, 0, stream>>>(btot, binBase);
    scatter_kernel<<<GBLK, 1024, 0, stream>>>(ei, ea, binBase, offs, edges);
    bounds_kernel<<<(NNODES + 1023) / 1024, 1024, 0, stream>>>(batch, endv);

    for (int l = 0; l < NLAYERS; ++l) {
        if (l == 0)
            agg_kernel<true><<<(NBINS + 3) / 4, 256, 0, stream>>>(x, nullptr, nullptr,
                                                                  binBase, edges, agg);
        else
            agg_kernel<false><<<(NBINS + 3) / 4, 256, 0, stream>>>(y, scaleA + (l - 1) * 64,
                                                                   shiftA + (l - 1) * 64,
                                                                   binBase, edges, agg);
        gemm_kernel<<<391, 256, 0, stream>>>(agg, W + l * 4096, b + l * 64, pa, y);
        stats_kernel<<<NGRAPHS, 512, 0, stream>>>(y, endv, gsum, pS, pQ);
        finalize_kernel<<<1, 1024, 0, stream>>>(gsum, pS, pQ, endv, bn_w + l * 64,
                                                bn_b + l * 64, scaleA + l * 64,
                                                shiftA + l * 64, out, l);
    }
}